// Round 7
// baseline (110.308 us; speedup 1.0000x reference)
//
#include <hip/hip_runtime.h>
#include <math.h>

// Tropical (max-plus) depthwise conv2d, 5x5, stride 1, pad 2, dilation 1.
// x: (8,32,224,224) f32, kernel: (32,1,5,5) f32, out: (8,32,224,224) f32.
// out[b,c,h,w] = max_{i,j} x[b,c,h-2+i, w-2+j] + kernel[c,0,4-i,4-j]
//
// R7: barrier-free, LDS-free. Each thread loads 8 center float4s (one
// unconditional clamped batch -> stays in flight together); column halo via
// __shfl_up/__shfl_down (taps only need v[2..9]); row halo redundancy (2x)
// absorbed by L1/L2 (verified R1: FETCH ~= 1x input at 3x overlap).
// No __syncthreads -> no per-block vmcnt(0) phase lock (R6's residual cost).

#define TC_B 8
#define TC_C 32
#define TC_H 224
#define TC_W 224
#define TC_WQ 56     // float4 per row
#define TC_HG 14     // 16 output rows per block

__global__ __launch_bounds__(256) void tropical_conv2d_kernel(
    const float* __restrict__ x, const float* __restrict__ kern,
    float* __restrict__ out) {
  const int tid = threadIdx.x;
  const int lane = tid & 63;
  const int yl = tid >> 6;          // wave 0..3
  const int blk = blockIdx.x;
  const int hg = blk % TC_HG;
  const int bc = blk / TC_HG;       // b*C + c (uniform)
  const int c = bc & (TC_C - 1);

  const float NEG = -INFINITY;
  const float* xp = x + (size_t)bc * (TC_H * TC_W);
  const int hbase = hg * 16 + yl * 4;        // first of 4 output rows
  const int cl = lane < TC_WQ ? lane : TC_WQ - 1;   // clamped f4 column

  // ---- 8 unconditional clamped loads (one batch, 32 dest VGPRs) ----
  float4 rB[8];
  #pragma unroll
  for (int rr = 0; rr < 8; ++rr) {
    int r = hbase - 2 + rr;
    r = r < 0 ? 0 : (r > TC_H - 1 ? TC_H - 1 : r);
    rB[rr] = ((const float4*)(xp + (size_t)r * TC_W))[cl];
  }

  // weights (uniform address -> scalar loads), overlap with vmem latency
  // w[i*5+j] = wflip[i][j] = kern[c][4-i][4-j]
  float w[25];
  #pragma unroll
  for (int q = 0; q < 25; ++q) w[q] = kern[c * 25 + 24 - q];

  // ---- row-OOB patch (branch-free) ----
  #pragma unroll
  for (int rr = 0; rr < 8; ++rr) {
    const int r = hbase - 2 + rr;
    const bool ok = (r >= 0) && (r < TC_H);
    rB[rr].x = ok ? rB[rr].x : NEG;
    rB[rr].y = ok ? rB[rr].y : NEG;
    rB[rr].z = ok ? rB[rr].z : NEG;
    rB[rr].w = ok ? rB[rr].w : NEG;
  }

  // ---- compute: 4 output rows x 4 cols, halo via shuffles ----
  float acc[4][4];
  #pragma unroll
  for (int o = 0; o < 4; ++o)
    #pragma unroll
    for (int k = 0; k < 4; ++k) acc[o][k] = NEG;

  const bool ledge = (lane == 0);
  const bool redge = (lane >= TC_WQ - 1);   // lane 55: cols 224/225 OOB

  #pragma unroll
  for (int ri = 0; ri < 8; ++ri) {
    // v[m] = x col 4*lane - 4 + m; taps use v[2..9] only
    float v2 = __shfl_up(rB[ri].z, 1);      // left lane's col 4l-2
    float v3 = __shfl_up(rB[ri].w, 1);      // left lane's col 4l-1
    float v8 = __shfl_down(rB[ri].x, 1);    // right lane's col 4l+4
    float v9 = __shfl_down(rB[ri].y, 1);    // right lane's col 4l+5
    v2 = ledge ? NEG : v2;
    v3 = ledge ? NEG : v3;
    v8 = redge ? NEG : v8;
    v9 = redge ? NEG : v9;
    const float v[8] = {v2, v3, rB[ri].x, rB[ri].y, rB[ri].z, rB[ri].w, v8, v9};
    // v[n] here = x col 4*lane - 2 + n, n in [0,8)

    #pragma unroll
    for (int o = 0; o < 4; ++o) {
      const int i = ri - o;                 // weight row (compile-time)
      if (i < 0 || i > 4) continue;
      #pragma unroll
      for (int k = 0; k < 4; ++k) {
        const float t0 = v[k + 0] + w[i * 5 + 0];
        const float t1 = v[k + 1] + w[i * 5 + 1];
        const float t2 = v[k + 2] + w[i * 5 + 2];
        const float t3 = v[k + 3] + w[i * 5 + 3];
        const float t4 = v[k + 4] + w[i * 5 + 4];
        acc[o][k] = fmaxf(fmaxf(fmaxf(acc[o][k], t0), t1),
                          fmaxf(fmaxf(t2, t3), t4));
      }
    }
  }

  if (lane < TC_WQ) {
    float* op = out + (size_t)bc * (TC_H * TC_W) + (size_t)hbase * TC_W;
    #pragma unroll
    for (int o = 0; o < 4; ++o) {
      ((float4*)(op + (size_t)o * TC_W))[lane] =
          make_float4(acc[o][0], acc[o][1], acc[o][2], acc[o][3]);
    }
  }
}

extern "C" void kernel_launch(void* const* d_in, const int* in_sizes, int n_in,
                              void* d_out, int out_size, void* d_ws, size_t ws_size,
                              hipStream_t stream) {
  const float* x = (const float*)d_in[0];
  const float* k = (const float*)d_in[1];
  float* out = (float*)d_out;

  dim3 block(256, 1, 1);
  dim3 grid(TC_B * TC_C * TC_HG, 1, 1);
  tropical_conv2d_kernel<<<grid, block, 0, stream>>>(x, k, out);
}